// Round 8
// baseline (346.830 us; speedup 1.0000x reference)
//
#include <hip/hip_runtime.h>
#include <hip/hip_bf16.h>

// Bahdanau additive attention, B=32, L=2048, H=1024, fp32 in/out.
// score_kernel v3 (m201-style geometry): block = 256l x 256o (o-split 4, XCD-sibling
// grouped), K-step 64, 16 steps. A (key) reg-staged fp32->bf16 (issue-early/write-late),
// B (Ua) staged block-wide via global_load_lds from a linearly pre-fragmented Ufrag2.
// 8 waves x (128l x 64o) = acc[4][2] f32x16. One barrier per K-step.

#define B_ 32
#define L_ 2048
#define H_ 1024

typedef __attribute__((ext_vector_type(8))) short bf16x8;   // 8 bf16 = 4 VGPRs
typedef __attribute__((ext_vector_type(16))) float f32x16;  // 32x32 MFMA acc
typedef __attribute__((ext_vector_type(4))) float f32x4;

__device__ inline unsigned pk_bf16(float a, float b) {
    unsigned r;
    asm("v_cvt_pk_bf16_f32 %0, %1, %2" : "=v"(r) : "v"(a), "v"(b));
    return r;
}

__device__ inline float fast_tanh(float x) {
    float e = __expf(2.f * x);
    return 1.f - 2.f * __builtin_amdgcn_rcpf(e + 1.f);
}

__device__ inline void glds16(const void* g, void* l) {
    // async global->LDS: per-lane GLOBAL address, wave-uniform LDS base + lane*16
    __builtin_amdgcn_global_load_lds(
        (const __attribute__((address_space(1))) uint32_t*)g,
        (__attribute__((address_space(3))) uint32_t*)l,
        16, 0, 0);
}

// ---- kernel 0a: Ua_w -> bf16 B-fragments, ordered for LINEAR 32KB chunk DMA:
// Ufrag2[oh 0..3][t 0..15][sl 0..3][j 0..7][lane 0..63][8]
// (s = t*4+sl, nb = oh*8+j; lane l holds B[k=(l>>5)*8+e][col=nb*32+(l&31)], h=s*16+k)
__global__ void prep_ua(const float* __restrict__ Ua, ushort* __restrict__ Ufrag2) {
    int slot = blockIdx.x * 256 + threadIdx.x;   // 131072 slots of 8 ushort
    int lane = slot & 63;
    int j    = (slot >> 6) & 7;
    int sl   = (slot >> 9) & 3;
    int t    = (slot >> 11) & 15;
    int oh   = (slot >> 15) & 3;
    int s  = t * 4 + sl;
    int nb = oh * 8 + j;
    int o = nb * 32 + (lane & 31);
    int h = s * 16 + (lane >> 5) * 8;
    const float* src = Ua + o * H_ + h;
    f32x4 f0 = *(const f32x4*)(src);
    f32x4 f1 = *(const f32x4*)(src + 4);
    uint4 pk;
    pk.x = pk_bf16(f0.x, f0.y);
    pk.y = pk_bf16(f0.z, f0.w);
    pk.z = pk_bf16(f1.x, f1.y);
    pk.w = pk_bf16(f1.z, f1.w);
    *(uint4*)(Ufrag2 + (size_t)slot * 8) = pk;
}

// ---- kernel 0b: qbuf[b][o] = query[b]·Wa_w[o] + Wa_b[o] + Ua_b[o]
__global__ void prep_q(const float* __restrict__ query, const float* __restrict__ Wa_w,
                       const float* __restrict__ Wa_b, const float* __restrict__ Ua_b,
                       float* __restrict__ qbuf) {
    int wid  = blockIdx.x * 4 + (threadIdx.x >> 6);
    int lane = threadIdx.x & 63;
    int b = wid >> 10, o = wid & 1023;
    const float* qrow = query + b * H_;
    const float* wrow = Wa_w + o * H_;
    float acc = 0.f;
    #pragma unroll
    for (int i = 0; i < 16; ++i) {
        int h = i * 64 + lane;
        acc += qrow[h] * wrow[h];
    }
    #pragma unroll
    for (int m = 1; m < 64; m <<= 1) acc += __shfl_xor(acc, m);
    if (lane == 0) qbuf[b * H_ + o] = acc + Wa_b[o] + Ua_b[o];
}

// ---- kernel 1: fused k-proj MFMA + tanh + va-dot -> pscore[oh][b][l]
__launch_bounds__(512, 2)
__global__ void score_kernel(const float* __restrict__ key, const ushort* __restrict__ Ufrag2,
                             const float* __restrict__ qbuf, const float* __restrict__ va_w,
                             float* __restrict__ pscore) {
    // Alds: [sl 0..3][mblk 0..7][lf 0..63][8]  (32 KB); Blds: [sl 0..3][j 0..7][lane][8] (32 KB)
    __shared__ ushort Alds[2][16384];
    __shared__ ushort Blds[2][16384];
    __shared__ float s_part[8][128];

    // sibling swizzle: 4 oh-blocks of one (b,lt) key tile share d%8 -> same XCD.
    int d    = blockIdx.x;                 // 1024 = 256 tiles * 4 oh
    int oh   = (d >> 3) & 3;
    int tile = (d & 7) | ((d >> 5) << 3);  // 0..255 = 32 b * 8 lt
    int b  = tile >> 3;
    int l0 = (tile & 7) * 256;
    int tid = threadIdx.x;
    int w = tid >> 6, lane = tid & 63;
    int wm = w >> 2, wn = w & 3;

    // A staging coords: row r = tid>>1 (0..255), col half c0 = (tid&1)*32
    int r    = tid >> 1;
    int c0   = (tid & 1) * 32;
    int mblk = r >> 5;
    const float* krow = key + ((size_t)b * L_ + (l0 + r)) * H_;

    const ushort* Uchunk0 = Ufrag2 + (size_t)(oh * 16) * 16384;   // per-t chunks of 16384 ushorts

    // ---- prologue: stage step 0 (A regs->convert->LDS, B via glds)
    {
        f32x4 ld[8];
        #pragma unroll
        for (int i = 0; i < 8; ++i) ld[i] = *(const f32x4*)(krow + c0 + 4 * i);
        #pragma unroll
        for (int i = 0; i < 4; ++i)
            glds16(Uchunk0 + (size_t)(w * 256 + i * 64 + lane) * 8,
                   &Blds[0][(w * 256 + i * 64) * 8]);
        #pragma unroll
        for (int e = 0; e < 4; ++e) {
            int hh = c0 + e * 8;
            int sl = hh >> 4;
            int lf = ((hh >> 3) & 1) * 32 + (r & 31);
            uint4 pk;
            pk.x = pk_bf16(ld[2*e].x,   ld[2*e].y);
            pk.y = pk_bf16(ld[2*e].z,   ld[2*e].w);
            pk.z = pk_bf16(ld[2*e+1].x, ld[2*e+1].y);
            pk.w = pk_bf16(ld[2*e+1].z, ld[2*e+1].w);
            *(uint4*)&Alds[0][((sl * 8 + mblk) * 64 + lf) * 8] = pk;
        }
    }
    __syncthreads();

    f32x16 acc[4][2] = {};

    #pragma unroll 2
    for (int t = 0; t < 16; ++t) {
        int cur = t & 1;
        int nxt = cur ^ 1;
        f32x4 ld[8];
        if (t < 15) {
            // issue A loads for t+1 (hidden under this step's MFMAs)
            #pragma unroll
            for (int i = 0; i < 8; ++i)
                ld[i] = *(const f32x4*)(krow + (t + 1) * 64 + c0 + 4 * i);
            // async B DMA for t+1 (per-lane global source!)
            const ushort* ch = Uchunk0 + (size_t)(t + 1) * 16384;
            #pragma unroll
            for (int i = 0; i < 4; ++i)
                glds16(ch + (size_t)(w * 256 + i * 64 + lane) * 8,
                       &Blds[nxt][(w * 256 + i * 64) * 8]);
        }
        __builtin_amdgcn_s_setprio(1);
        #pragma unroll
        for (int sl = 0; sl < 4; ++sl) {
            bf16x8 a0 = *(const bf16x8*)&Alds[cur][((sl * 8 + wm * 4 + 0) * 64 + lane) * 8];
            bf16x8 a1 = *(const bf16x8*)&Alds[cur][((sl * 8 + wm * 4 + 1) * 64 + lane) * 8];
            bf16x8 a2 = *(const bf16x8*)&Alds[cur][((sl * 8 + wm * 4 + 2) * 64 + lane) * 8];
            bf16x8 a3 = *(const bf16x8*)&Alds[cur][((sl * 8 + wm * 4 + 3) * 64 + lane) * 8];
            bf16x8 b0 = *(const bf16x8*)&Blds[cur][((sl * 8 + wn * 2 + 0) * 64 + lane) * 8];
            bf16x8 b1 = *(const bf16x8*)&Blds[cur][((sl * 8 + wn * 2 + 1) * 64 + lane) * 8];
            acc[0][0] = __builtin_amdgcn_mfma_f32_32x32x16_bf16(a0, b0, acc[0][0], 0, 0, 0);
            acc[1][0] = __builtin_amdgcn_mfma_f32_32x32x16_bf16(a1, b0, acc[1][0], 0, 0, 0);
            acc[2][0] = __builtin_amdgcn_mfma_f32_32x32x16_bf16(a2, b0, acc[2][0], 0, 0, 0);
            acc[3][0] = __builtin_amdgcn_mfma_f32_32x32x16_bf16(a3, b0, acc[3][0], 0, 0, 0);
            acc[0][1] = __builtin_amdgcn_mfma_f32_32x32x16_bf16(a0, b1, acc[0][1], 0, 0, 0);
            acc[1][1] = __builtin_amdgcn_mfma_f32_32x32x16_bf16(a1, b1, acc[1][1], 0, 0, 0);
            acc[2][1] = __builtin_amdgcn_mfma_f32_32x32x16_bf16(a2, b1, acc[2][1], 0, 0, 0);
            acc[3][1] = __builtin_amdgcn_mfma_f32_32x32x16_bf16(a3, b1, acc[3][1], 0, 0, 0);
        }
        __builtin_amdgcn_s_setprio(0);
        if (t < 15) {
            // convert + write A(t+1); barrier drains glds + makes writes visible
            #pragma unroll
            for (int e = 0; e < 4; ++e) {
                int hh = c0 + e * 8;
                int sl = hh >> 4;
                int lf = ((hh >> 3) & 1) * 32 + (r & 31);
                uint4 pk;
                pk.x = pk_bf16(ld[2*e].x,   ld[2*e].y);
                pk.y = pk_bf16(ld[2*e].z,   ld[2*e].w);
                pk.z = pk_bf16(ld[2*e+1].x, ld[2*e+1].y);
                pk.w = pk_bf16(ld[2*e+1].z, ld[2*e+1].w);
                *(uint4*)&Alds[nxt][((sl * 8 + mblk) * 64 + lf) * 8] = pk;
            }
            __syncthreads();
        }
    }

    // ---- epilogue: rowsum over this wave's 64 o-cols
    #pragma unroll
    for (int mi = 0; mi < 4; ++mi) {
        float rowsum[16];
        #pragma unroll
        for (int rg = 0; rg < 16; ++rg) rowsum[rg] = 0.f;
        #pragma unroll
        for (int ni = 0; ni < 2; ++ni) {
            int col = oh * 256 + (wn * 2 + ni) * 32 + (lane & 31);
            float qv  = qbuf[b * H_ + col];
            float vav = va_w[col];
            #pragma unroll
            for (int rg = 0; rg < 16; ++rg)
                rowsum[rg] += vav * fast_tanh(qv + acc[mi][ni][rg]);
        }
        #pragma unroll
        for (int rg = 0; rg < 16; ++rg) {
            float v = rowsum[rg];
            v += __shfl_xor(v, 1);  v += __shfl_xor(v, 2);  v += __shfl_xor(v, 4);
            v += __shfl_xor(v, 8);  v += __shfl_xor(v, 16);
            if ((lane & 31) == 0) {
                int row = mi * 32 + (rg & 3) + 8 * (rg >> 2) + 4 * (lane >> 5);
                s_part[w][row] = v;   // wave's l-rows: wm*128 + row
            }
        }
    }
    __syncthreads();
    if (tid < 256) {
        int wmf = tid >> 7;
        int rl  = tid & 127;
        float s = s_part[wmf * 4 + 0][rl] + s_part[wmf * 4 + 1][rl]
                + s_part[wmf * 4 + 2][rl] + s_part[wmf * 4 + 3][rl];
        pscore[((size_t)oh * B_ + b) * L_ + l0 + tid] = s;
    }
}

// ---- kernel 2: combine 4 o-quarter partials + bias + mask + softmax -> attn [B][L]
__global__ void softmax_kernel(const float* __restrict__ pscore, const float* __restrict__ va_b,
                               const int* __restrict__ mask, float* __restrict__ attn) {
    __shared__ float red[16];
    int b = blockIdx.x;
    int tid = threadIdx.x;    // 256
    float vab = va_b[0];
    float v[8];
    float mx = -3e38f;
    #pragma unroll
    for (int i = 0; i < 8; ++i) {
        int l = tid + i * 256;
        float s = pscore[b * L_ + l]
                + pscore[((size_t)1 * B_ + b) * L_ + l]
                + pscore[((size_t)2 * B_ + b) * L_ + l]
                + pscore[((size_t)3 * B_ + b) * L_ + l] + vab;
        int m = mask[b * L_ + l];
        v[i] = (m == 0) ? -1e10f : s;
        mx = fmaxf(mx, v[i]);
    }
    #pragma unroll
    for (int m = 1; m < 64; m <<= 1) mx = fmaxf(mx, __shfl_xor(mx, m));
    if ((tid & 63) == 0) red[tid >> 6] = mx;
    __syncthreads();
    mx = fmaxf(fmaxf(red[0], red[1]), fmaxf(red[2], red[3]));
    float sum = 0.f;
    #pragma unroll
    for (int i = 0; i < 8; ++i) { v[i] = __expf(v[i] - mx); sum += v[i]; }
    #pragma unroll
    for (int m = 1; m < 64; m <<= 1) sum += __shfl_xor(sum, m);
    if ((tid & 63) == 0) red[8 + (tid >> 6)] = sum;
    __syncthreads();
    sum = red[8] + red[9] + red[10] + red[11];
    float inv = 1.f / sum;
    #pragma unroll
    for (int i = 0; i < 8; ++i) attn[b * L_ + tid + i * 256] = v[i] * inv;
}

// ---- kernel 3: partial context over 128-l chunks -> partial[b*16+ch][1024]
__global__ void context_kernel(const float* __restrict__ attn, const float* __restrict__ value,
                               float* __restrict__ partial) {
    int bid = blockIdx.x;            // 512 = 32 b * 16 chunks
    int b = bid >> 4, ch = bid & 15;
    int l0 = ch * 128;
    int tid = threadIdx.x;           // 256
    f32x4 acc = {0.f, 0.f, 0.f, 0.f};
    const float* vbase = value + ((size_t)b * L_ + l0) * H_ + tid * 4;
    const float* arow  = attn + b * L_ + l0;
    for (int l = 0; l < 128; ++l) {
        float a = arow[l];
        f32x4 vv = *(const f32x4*)(vbase + (size_t)l * H_);
        acc.x += a * vv.x; acc.y += a * vv.y; acc.z += a * vv.z; acc.w += a * vv.w;
    }
    *(f32x4*)(partial + (size_t)bid * H_ + tid * 4) = acc;
}

// ---- kernel 4: reduce 16 partials -> out [B][1][H]
__global__ void reduce_kernel(const float* __restrict__ partial, float* __restrict__ out) {
    int t = blockIdx.x * 256 + threadIdx.x;   // 32768
    int b = t >> 10, h = t & 1023;
    float s = 0.f;
    #pragma unroll
    for (int c = 0; c < 16; ++c) s += partial[(size_t)(b * 16 + c) * H_ + h];
    out[t] = s;
}

extern "C" void kernel_launch(void* const* d_in, const int* in_sizes, int n_in,
                              void* d_out, int out_size, void* d_ws, size_t ws_size,
                              hipStream_t stream) {
    const float* query = (const float*)d_in[0];
    const float* key   = (const float*)d_in[1];
    const float* value = (const float*)d_in[2];
    const int*   mask  = (const int*)d_in[3];
    const float* Wa_w  = (const float*)d_in[4];
    const float* Wa_b  = (const float*)d_in[5];
    const float* Ua_w  = (const float*)d_in[6];
    const float* Ua_b  = (const float*)d_in[7];
    const float* va_w  = (const float*)d_in[8];
    const float* va_b  = (const float*)d_in[9];
    float* out = (float*)d_out;

    char* ws = (char*)d_ws;
    ushort* Ufrag2   = (ushort*)ws;                                   // 2 MB
    float*  qbuf     = (float*)(ws + (2u << 20));                     // 128 KB
    float*  pscore   = (float*)(ws + (2u << 20) + (128u << 10));      // 1 MB (4 quarters)
    float*  attnb    = (float*)(ws + (3u << 20) + (128u << 10));      // 256 KB
    float*  partial  = (float*)(ws + (3u << 20) + (384u << 10));      // 2 MB

    hipLaunchKernelGGL(prep_ua,        dim3(512),  dim3(256), 0, stream, Ua_w, Ufrag2);
    hipLaunchKernelGGL(prep_q,         dim3(8192), dim3(256), 0, stream, query, Wa_w, Wa_b, Ua_b, qbuf);
    hipLaunchKernelGGL(score_kernel,   dim3(1024), dim3(512), 0, stream, key, Ufrag2, qbuf, va_w, pscore);
    hipLaunchKernelGGL(softmax_kernel, dim3(32),   dim3(256), 0, stream, pscore, va_b, mask, attnb);
    hipLaunchKernelGGL(context_kernel, dim3(512),  dim3(256), 0, stream, attnb, value, partial);
    hipLaunchKernelGGL(reduce_kernel,  dim3(128),  dim3(256), 0, stream, partial, out);
}